// Round 1
// baseline (3009.720 us; speedup 1.0000x reference)
//
#include <hip/hip_runtime.h>
#include <math.h>

// Problem constants (S2VT: 2-layer GRU encoder + 3-step decoder)
#define Bsz 64
#define Tt  32
#define Dv  2048
#define Hd  1024
#define G3  3072   // 3*Hd
#define Vv  20000
#define ML  3

// ---------------------------------------------------------------------------
// Big GEMM: C[M,N] = A[M,K] (row-major, lda) * W[N,K]^T (row-major, ldw) + bias
// 64x64 tile, BK=16, 256 threads, 4x4 microtile. Requires M%64==0, N%64==0,
// K%16==0, lda/ldw%4==0.
// ---------------------------------------------------------------------------
__global__ __launch_bounds__(256)
void gemm_nt_64x64(const float* __restrict__ A, int lda,
                   const float* __restrict__ W, int ldw,
                   const float* __restrict__ bias,
                   float* __restrict__ C, int ldc, int K)
{
    __shared__ __align__(16) float As[16][72];   // [k][m], pad 72 keeps b128 alignment
    __shared__ __align__(16) float Ws[16][72];   // [k][n]
    const int tid = threadIdx.x;
    const int n0 = blockIdx.x * 64;
    const int m0 = blockIdx.y * 64;
    const int tx = tid & 15;          // n-dir
    const int ty = tid >> 4;          // m-dir
    const int r  = tid >> 2;          // staging row 0..63
    const int c4 = (tid & 3) << 2;    // staging k 0,4,8,12
    float acc[4][4] = {};

    for (int k0 = 0; k0 < K; k0 += 16) {
        float4 a = *(const float4*)(A + (size_t)(m0 + r) * lda + k0 + c4);
        float4 w = *(const float4*)(W + (size_t)(n0 + r) * ldw + k0 + c4);
        As[c4+0][r] = a.x; As[c4+1][r] = a.y; As[c4+2][r] = a.z; As[c4+3][r] = a.w;
        Ws[c4+0][r] = w.x; Ws[c4+1][r] = w.y; Ws[c4+2][r] = w.z; Ws[c4+3][r] = w.w;
        __syncthreads();
        #pragma unroll
        for (int kk = 0; kk < 16; ++kk) {
            float av[4], wv[4];
            #pragma unroll
            for (int i = 0; i < 4; ++i) av[i] = As[kk][ty*4 + i];
            #pragma unroll
            for (int j = 0; j < 4; ++j) wv[j] = Ws[kk][tx*4 + j];
            #pragma unroll
            for (int i = 0; i < 4; ++i)
                #pragma unroll
                for (int j = 0; j < 4; ++j)
                    acc[i][j] = fmaf(av[i], wv[j], acc[i][j]);
        }
        __syncthreads();
    }
    #pragma unroll
    for (int i = 0; i < 4; ++i) {
        const int m = m0 + ty*4 + i;
        #pragma unroll
        for (int j = 0; j < 4; ++j) {
            const int n = n0 + tx*4 + j;
            C[(size_t)m * ldc + n] = acc[i][j] + bias[n];
        }
    }
}

// ---------------------------------------------------------------------------
// Skinny GEMM for M=64 with column-major A (A[m][k] = Acm[k*64 + m], i.e. the
// transposed hidden state hT[H][B] is consumed directly).
// C[64,N] = A * W[N,K]^T + bias.  BN=32, BK=32. Requires N%32==0, K%32==0.
// ---------------------------------------------------------------------------
__global__ __launch_bounds__(256)
void gemm_skinny(const float* __restrict__ Acm,
                 const float* __restrict__ W, int ldw,
                 const float* __restrict__ bias,
                 float* __restrict__ C, int ldc, int K)
{
    __shared__ __align__(16) float As[32 * 64];  // [kk][m] flat (matches Acm layout)
    __shared__ __align__(16) float Ws[32][33];   // [kk][n]
    const int tid = threadIdx.x;
    const int n0 = blockIdx.x * 32;
    const int tx = tid & 15;   // 2 cols each
    const int ty = tid >> 4;   // 4 rows each
    float acc[4][2] = {};

    for (int k0 = 0; k0 < K; k0 += 32) {
        // A chunk: flat copy of 2048 floats (coalesced b128 both sides)
        const float4* src = (const float4*)(Acm + (size_t)k0 * 64);
        float4* dst = (float4*)As;
        dst[tid]       = src[tid];
        dst[tid + 256] = src[tid + 256];
        // W chunk: 32 rows x 32 k
        {
            const int r = tid >> 3;          // 0..31
            const int c = (tid & 7) << 2;    // 0..28
            float4 w = *(const float4*)(W + (size_t)(n0 + r) * ldw + k0 + c);
            Ws[c+0][r] = w.x; Ws[c+1][r] = w.y; Ws[c+2][r] = w.z; Ws[c+3][r] = w.w;
        }
        __syncthreads();
        #pragma unroll
        for (int kk = 0; kk < 32; ++kk) {
            float av[4], wv[2];
            #pragma unroll
            for (int i = 0; i < 4; ++i) av[i] = As[kk*64 + ty*4 + i];
            wv[0] = Ws[kk][tx*2 + 0];
            wv[1] = Ws[kk][tx*2 + 1];
            #pragma unroll
            for (int i = 0; i < 4; ++i) {
                acc[i][0] = fmaf(av[i], wv[0], acc[i][0]);
                acc[i][1] = fmaf(av[i], wv[1], acc[i][1]);
            }
        }
        __syncthreads();
    }
    #pragma unroll
    for (int i = 0; i < 4; ++i) {
        const int m = ty*4 + i;
        #pragma unroll
        for (int j = 0; j < 2; ++j) {
            const int n = n0 + tx*2 + j;
            C[(size_t)m * ldc + n] = acc[i][j] + bias[n];
        }
    }
}

// ---------------------------------------------------------------------------
// One fused GRU step. Hidden state is stored TRANSPOSED: hT[H][B] so the inner
// product reads hT[k][b] with lanes = b (coalesced, 2-way LDS bank alias = free).
//   hp   = h @ W_hh^T + b_hh      (3 gate strips computed in-kernel)
//   r = sig(xr+hr); z = sig(xz+hz); n = tanh(xn + r*hn); h' = (1-z)n + z h
// xp row for batch b is xp[b*xp_stride + (gate*Hd + j)]; xp_stride==0 gives the
// broadcast-bias decode case (xp = b_ih1).
// grid = Hd/4 blocks, 256 threads; wave w handles column j = blk*4 + w.
// Optionally writes out_seq[t][b][j] (layout (T,B,H)) for the layer-2 input.
// ---------------------------------------------------------------------------
__global__ __launch_bounds__(256)
void gru_step(const float* __restrict__ xp, int xp_stride,
              const float* __restrict__ hT_in,
              const float* __restrict__ W_hh,   // [3H, H] row-major
              const float* __restrict__ b_hh,
              float* __restrict__ hT_out,
              float* __restrict__ out_seq,      // nullable, (T,B,H)
              int t)
{
    __shared__ __align__(16) float hs[128 * 64];   // [kk][b]
    __shared__ __align__(16) float Ws[3 * 4 * 128];// [gate][wave][kk]
    const int tid = threadIdx.x;
    const int b  = tid & 63;
    const int w  = tid >> 6;
    const int j0 = blockIdx.x * 4;
    const int j  = j0 + w;
    float accr = 0.f, accz = 0.f, accn = 0.f;

    for (int c = 0; c < Hd / 128; ++c) {
        const int k0 = c * 128;
        {   // stage h chunk: 8192 floats, flat coalesced copy
            const float4* src = (const float4*)(hT_in + (size_t)k0 * 64);
            float4* dst = (float4*)hs;
            #pragma unroll
            for (int i = 0; i < 8; ++i) dst[tid + i*256] = src[tid + i*256];
        }
        {   // stage W slice: 3 gates x 4 cols x 128 k
            #pragma unroll
            for (int i = 0; i < 6; ++i) {
                const int q  = tid + i * 256;
                const int g  = q >> 9;
                const int ww = (q >> 7) & 3;
                const int kk = q & 127;
                Ws[q] = W_hh[(size_t)(g * Hd + j0 + ww) * Hd + k0 + kk];
            }
        }
        __syncthreads();
        const float* wr = &Ws[(0*4 + w) * 128];
        const float* wz = &Ws[(1*4 + w) * 128];
        const float* wn = &Ws[(2*4 + w) * 128];
        #pragma unroll 4
        for (int kk = 0; kk < 128; ++kk) {
            const float hv = hs[kk*64 + b];
            accr = fmaf(hv, wr[kk], accr);
            accz = fmaf(hv, wz[kk], accz);
            accn = fmaf(hv, wn[kk], accn);
        }
        __syncthreads();
    }

    const float xr  = xp[(size_t)b * xp_stride + j];
    const float xz  = xp[(size_t)b * xp_stride + Hd + j];
    const float xn  = xp[(size_t)b * xp_stride + 2*Hd + j];
    const float hr  = accr + b_hh[j];
    const float hz  = accz + b_hh[Hd + j];
    const float hn_ = accn + b_hh[2*Hd + j];
    const float rg  = 1.f / (1.f + __expf(-(xr + hr)));
    const float zg  = 1.f / (1.f + __expf(-(xz + hz)));
    const float ng  = tanhf(xn + rg * hn_);
    const float hprev = hT_in[(size_t)j * 64 + b];
    const float hnew  = (1.f - zg) * ng + zg * hprev;
    hT_out[(size_t)j * 64 + b] = hnew;                       // coalesced
    if (out_seq) out_seq[((size_t)t * 64 + b) * Hd + j] = hnew; // 1 scattered store/wave
}

// ---------------------------------------------------------------------------
// Row log-softmax: out[b][step][v] = logits[b][v] - (max + log(sum exp(x-max)))
// grid = 64 rows, 256 threads (4 waves).
// ---------------------------------------------------------------------------
__global__ __launch_bounds__(256)
void log_softmax_k(const float* __restrict__ logits, float* __restrict__ out, int step)
{
    __shared__ float red[4];
    const int b   = blockIdx.x;
    const int tid = threadIdx.x;
    const float* row = logits + (size_t)b * Vv;

    float m = -1e30f;
    for (int v = tid; v < Vv; v += 256) m = fmaxf(m, row[v]);
    #pragma unroll
    for (int off = 32; off > 0; off >>= 1) m = fmaxf(m, __shfl_down(m, off, 64));
    if ((tid & 63) == 0) red[tid >> 6] = m;
    __syncthreads();
    m = fmaxf(fmaxf(red[0], red[1]), fmaxf(red[2], red[3]));
    __syncthreads();

    float s = 0.f;
    for (int v = tid; v < Vv; v += 256) s += expf(row[v] - m);
    #pragma unroll
    for (int off = 32; off > 0; off >>= 1) s += __shfl_down(s, off, 64);
    if ((tid & 63) == 0) red[tid >> 6] = s;
    __syncthreads();
    s = red[0] + red[1] + red[2] + red[3];
    const float lse = m + logf(s);

    float* orow = out + ((size_t)b * ML + step) * Vv;
    for (int v = tid; v < Vv; v += 256) orow[v] = row[v] - lse;
}

// ---------------------------------------------------------------------------
extern "C" void kernel_launch(void* const* d_in, const int* in_sizes, int n_in,
                              void* d_out, int out_size, void* d_ws, size_t ws_size,
                              hipStream_t stream)
{
    (void)in_sizes; (void)n_in; (void)out_size; (void)ws_size;
    const float* vid   = (const float*)d_in[0];
    const float* W_ih1 = (const float*)d_in[1];
    const float* W_hh1 = (const float*)d_in[2];
    const float* b_ih1 = (const float*)d_in[3];
    const float* b_hh1 = (const float*)d_in[4];
    const float* W_ih2 = (const float*)d_in[5];   // (3072, 1536); only first 1024 cols used
    const float* W_hh2 = (const float*)d_in[6];
    const float* b_ih2 = (const float*)d_in[7];
    const float* b_hh2 = (const float*)d_in[8];
    const float* W_obj = (const float*)d_in[9];
    const float* b_obj = (const float*)d_in[10];
    const float* W_rel = (const float*)d_in[11];
    const float* b_rel = (const float*)d_in[12];
    float* out = (float*)d_out;

    // workspace carve-up (floats); total ~10.1M floats = 40.5 MB
    float* ws     = (float*)d_ws;
    float* xp1    = ws;                        // (B,T,3H) 6,291,456 — reused as xp2 (T,B,3H)
    float* out1   = xp1  + (size_t)2048 * G3;  // (T,B,H)  2,097,152
    float* h1a    = out1 + (size_t)2048 * Hd;  // hT layouts [H][B]
    float* h1b    = h1a  + 64 * Hd;
    float* h2a    = h1b  + 64 * Hd;
    float* h2b    = h2a  + 64 * Hd;
    float* xp2t   = h2b  + 64 * Hd;            // (B,3H) decode scratch
    float* logits = xp2t + 64 * G3;            // (B,V)

    hipMemsetAsync(h1a, 0, 64 * Hd * sizeof(float), stream);
    hipMemsetAsync(h2a, 0, 64 * Hd * sizeof(float), stream);

    // Phase 1: xp1 = vid @ W_ih1^T + b_ih1   (M=2048, K=2048, N=3072)
    gemm_nt_64x64<<<dim3(G3/64, 2048/64), 256, 0, stream>>>(
        vid, Dv, W_ih1, Dv, b_ih1, xp1, G3, Dv);

    // Phase 2: layer-1 scan (xp1 row for (b,t): xp1 + t*3H + b*(T*3H))
    float* h = h1a; float* hn = h1b;
    for (int t = 0; t < Tt; ++t) {
        gru_step<<<Hd/4, 256, 0, stream>>>(
            xp1 + (size_t)t * G3, Tt * G3, h, W_hh1, b_hh1, hn, out1, t);
        float* tmp = h; h = hn; hn = tmp;
    }

    // Phase 3: xp2 = out1 @ W_ih2[:, :H]^T + b_ih2  (M=2048, K=1024, N=3072)
    float* xp2 = xp1;  // alias: xp1 dead after scan 1
    gemm_nt_64x64<<<dim3(G3/64, 2048/64), 256, 0, stream>>>(
        out1, Hd, W_ih2, Hd + 512, b_ih2, xp2, G3, Hd);

    // Phase 4: layer-2 scan (xp2 is (T,B,3H))
    float* g = h2a; float* gn = h2b;
    for (int t = 0; t < Tt; ++t) {
        gru_step<<<Hd/4, 256, 0, stream>>>(
            xp2 + (size_t)t * 64 * G3, G3, g, W_hh2, b_hh2, gn, nullptr, 0);
        float* tmp = g; g = gn; gn = tmp;
    }

    // Phase 5: decode, 3 steps
    for (int i = 0; i < ML; ++i) {
        // h1 = GRU1(bias-only xp): xp_stride=0 broadcasts b_ih1 to every batch row
        gru_step<<<Hd/4, 256, 0, stream>>>(b_ih1, 0, h, W_hh1, b_hh1, hn, nullptr, 0);
        { float* tmp = h; h = hn; hn = tmp; }
        // xp2t = h1 @ W_ih2[:, :H]^T + b_ih2  (A = hT col-major)
        gemm_skinny<<<G3/32, 256, 0, stream>>>(h, W_ih2, Hd + 512, b_ih2, xp2t, G3, Hd);
        // h2 = GRU2(xp2t)
        gru_step<<<Hd/4, 256, 0, stream>>>(xp2t, G3, g, W_hh2, b_hh2, gn, nullptr, 0);
        { float* tmp = g; g = gn; gn = tmp; }
        // logits = h2 @ Wo^T + bo
        const float* Wo = (i == 1) ? W_rel : W_obj;
        const float* bo = (i == 1) ? b_rel : b_obj;
        gemm_skinny<<<Vv/32, 256, 0, stream>>>(g, Wo, Hd, bo, logits, Vv, Hd);
        // out[b][i][:] = log_softmax(logits[b])
        log_softmax_k<<<64, 256, 0, stream>>>(logits, out, i);
    }
}

// Round 2
// 1617.763 us; speedup vs baseline: 1.8604x; 1.8604x over previous
//
#include <hip/hip_runtime.h>
#include <math.h>

#define Bsz 64
#define Tt  32
#define Dv  2048
#define Hd  1024
#define G3  3072
#define Vv  20000
#define ML  3

typedef __attribute__((ext_vector_type(8))) short bf16x8;
typedef __attribute__((ext_vector_type(4))) float f32x4;
#define MFMA(a,b,c) __builtin_amdgcn_mfma_f32_16x16x32_bf16(a,b,c,0,0,0)

__device__ __forceinline__ short f2bf(float f) {
    union { float f; unsigned u; } v; v.f = f;
    unsigned r = v.u + 0x7fffu + ((v.u >> 16) & 1u);
    return (short)(r >> 16);
}
__device__ __forceinline__ float bf2f(short s) {
    union { unsigned u; float f; } v; v.u = ((unsigned)(unsigned short)s) << 16;
    return v.f;
}

// ---------------------------------------------------------------------------
// fp32 -> bf16 conversion, 8 elems/thread, optional row slicing (for W_ih2).
// ---------------------------------------------------------------------------
__global__ __launch_bounds__(256)
void cvt_f32_bf16(const float* __restrict__ src, short* __restrict__ dst,
                  long total8, long cols8, int src_ld, int dst_ld)
{
    long i = (long)blockIdx.x * 256 + threadIdx.x;
    if (i >= total8) return;
    long r = i / cols8; long c = i - r * cols8;
    const float* s = src + r * (long)src_ld + c * 8;
    float4 x = *(const float4*)s;
    float4 y = *(const float4*)(s + 4);
    bf16x8 o;
    o[0]=f2bf(x.x); o[1]=f2bf(x.y); o[2]=f2bf(x.z); o[3]=f2bf(x.w);
    o[4]=f2bf(y.x); o[5]=f2bf(y.y); o[6]=f2bf(y.z); o[7]=f2bf(y.w);
    *(bf16x8*)(dst + r * (long)dst_ld + c * 8) = o;
}

// ---------------------------------------------------------------------------
// Big MFMA GEMM: C[M,N] = A[M,K]bf16 * W[N,K]bf16^T + bias.  128x128 tile,
// BK=32, 256 thr = 4 waves (2x2 quadrants of 64x64), reg-staged LDS with
// 80B-padded rows (40 shorts) -> conflict-free ds_read_b128 without swizzle.
// ---------------------------------------------------------------------------
__global__ __launch_bounds__(256)
void gemm_mfma_128(const short* __restrict__ A, int lda,
                   const short* __restrict__ W, int ldw,
                   const float* __restrict__ bias,
                   float* __restrict__ C, int ldc, int K)
{
    __shared__ __align__(16) short As[128 * 40];
    __shared__ __align__(16) short Bs[128 * 40];
    const int tid = threadIdx.x;
    const int w = tid >> 6, l = tid & 63;
    const int wm = w >> 1, wn = w & 1;
    const int lr = l & 15, lg = l >> 4;
    const int m0 = blockIdx.y * 128, n0 = blockIdx.x * 128;
    const int sm = tid >> 2;        // staging row 0..63 (+64 on 2nd issue)
    const int skg = tid & 3;        // staging k-group

    f32x4 acc[4][4] = {};

    for (int k0 = 0; k0 < K; k0 += 32) {
        #pragma unroll
        for (int i = 0; i < 2; ++i) {
            const int m = i * 64 + sm;
            bf16x8 av = *(const bf16x8*)(A + (size_t)(m0 + m) * lda + k0 + skg * 8);
            bf16x8 wv = *(const bf16x8*)(W + (size_t)(n0 + m) * ldw + k0 + skg * 8);
            *(bf16x8*)(As + m * 40 + skg * 8) = av;
            *(bf16x8*)(Bs + m * 40 + skg * 8) = wv;
        }
        __syncthreads();
        bf16x8 af[4], bfr[4];
        #pragma unroll
        for (int mt = 0; mt < 4; ++mt) {
            const int m = wm * 64 + mt * 16 + lr;
            const int n = wn * 64 + mt * 16 + lr;
            af[mt]  = *(const bf16x8*)(As + m * 40 + lg * 8);
            bfr[mt] = *(const bf16x8*)(Bs + n * 40 + lg * 8);
        }
        #pragma unroll
        for (int mt = 0; mt < 4; ++mt)
            #pragma unroll
            for (int nt = 0; nt < 4; ++nt)
                acc[mt][nt] = MFMA(af[mt], bfr[nt], acc[mt][nt]);
        __syncthreads();
    }

    #pragma unroll
    for (int mt = 0; mt < 4; ++mt)
        #pragma unroll
        for (int nt = 0; nt < 4; ++nt)
            #pragma unroll
            for (int v = 0; v < 4; ++v) {
                const int m = m0 + wm * 64 + mt * 16 + lg * 4 + v;
                const int n = n0 + wn * 64 + nt * 16 + lr;
                C[(size_t)m * ldc + n] = acc[mt][nt][v] + bias[n];
            }
}

// ---------------------------------------------------------------------------
// Fused GRU step, MFMA, no LDS (h 128KB + W 6MB are L2-resident).
// h stored row-major bf16 [64][1024]. Block = 4 waves, wave = M-tile mt;
// block covers 16 gate-columns j for all 3 gates. grid = 64.
// xp row index = b*xp_rs + xp_off (xp_rs=0 -> broadcast bias vector).
// ---------------------------------------------------------------------------
__global__ __launch_bounds__(256)
void gru_step_mfma(const float* __restrict__ xp, int xp_rs, int xp_off,
                   const short* __restrict__ h_in,
                   const short* __restrict__ Whh,   // bf16 [3072][1024]
                   const float* __restrict__ b_hh,
                   short* __restrict__ h_out,
                   short* __restrict__ out_seq,     // bf16 (T*64,1024) or null
                   int t)
{
    const int tid = threadIdx.x;
    const int mt = tid >> 6;
    const int l  = tid & 63;
    const int lr = l & 15, lg = l >> 4;
    const int j0 = blockIdx.x * 16;

    const short* pa  = h_in + (size_t)(mt * 16 + lr) * Hd + lg * 8;
    const short* pb0 = Whh + (size_t)(0 * Hd + j0 + lr) * Hd + lg * 8;
    const short* pb1 = Whh + (size_t)(1 * Hd + j0 + lr) * Hd + lg * 8;
    const short* pb2 = Whh + (size_t)(2 * Hd + j0 + lr) * Hd + lg * 8;

    f32x4 acc0 = {}, acc1 = {}, acc2 = {};

    bf16x8 A0  = *(const bf16x8*)(pa);
    bf16x8 B00 = *(const bf16x8*)(pb0);
    bf16x8 B01 = *(const bf16x8*)(pb1);
    bf16x8 B02 = *(const bf16x8*)(pb2);
    bf16x8 A1  = *(const bf16x8*)(pa + 32);
    bf16x8 B10 = *(const bf16x8*)(pb0 + 32);
    bf16x8 B11 = *(const bf16x8*)(pb1 + 32);
    bf16x8 B12 = *(const bf16x8*)(pb2 + 32);

    #pragma unroll
    for (int ks = 0; ks < 32; ks += 2) {
        const int k2 = ((ks + 2) & 31) * 32;
        const int k3 = ((ks + 3) & 31) * 32;
        acc0 = MFMA(A0, B00, acc0);
        acc1 = MFMA(A0, B01, acc1);
        acc2 = MFMA(A0, B02, acc2);
        A0  = *(const bf16x8*)(pa  + k2);
        B00 = *(const bf16x8*)(pb0 + k2);
        B01 = *(const bf16x8*)(pb1 + k2);
        B02 = *(const bf16x8*)(pb2 + k2);
        acc0 = MFMA(A1, B10, acc0);
        acc1 = MFMA(A1, B11, acc1);
        acc2 = MFMA(A1, B12, acc2);
        A1  = *(const bf16x8*)(pa  + k3);
        B10 = *(const bf16x8*)(pb0 + k3);
        B11 = *(const bf16x8*)(pb1 + k3);
        B12 = *(const bf16x8*)(pb2 + k3);
    }

    const int j = j0 + lr;
    #pragma unroll
    for (int v = 0; v < 4; ++v) {
        const int b = mt * 16 + lg * 4 + v;
        const float* xrow = xp + (size_t)(b * xp_rs + xp_off) * G3;
        const float xr = xrow[j];
        const float xz = xrow[Hd + j];
        const float xn = xrow[2 * Hd + j];
        const float hr = acc0[v] + b_hh[j];
        const float hz = acc1[v] + b_hh[Hd + j];
        const float hn = acc2[v] + b_hh[2 * Hd + j];
        const float rg = 1.f / (1.f + __expf(-(xr + hr)));
        const float zg = 1.f / (1.f + __expf(-(xz + hz)));
        const float ng = tanhf(xn + rg * hn);
        const float hp = bf2f(h_in[(size_t)b * Hd + j]);
        const float hv = (1.f - zg) * ng + zg * hp;
        const short hb = f2bf(hv);
        h_out[(size_t)b * Hd + j] = hb;
        if (out_seq) out_seq[((size_t)t * 64 + b) * Hd + j] = hb;
    }
}

// ---------------------------------------------------------------------------
// Skinny MFMA GEMM: C[64,N]f32 = A[64,1024]bf16 * W[N,1024]^T + bias.
// 1 wave/block (W read exactly once), block covers 16 cols, wave does all 4
// M-tiles. WF32: W is fp32, converted in-register (used for W_obj/W_rel).
// ---------------------------------------------------------------------------
template<bool WF32>
__global__ __launch_bounds__(64)
void skinny_mfma(const short* __restrict__ A,
                 const void* __restrict__ Wp,
                 const float* __restrict__ bias,
                 float* __restrict__ C, int N)
{
    const int l = threadIdx.x;
    const int lr = l & 15, lg = l >> 4;
    const int n0 = blockIdx.x * 16;
    const size_t wrow = (size_t)(n0 + lr) * Hd + lg * 8;
    const short* pa = A + (size_t)lr * Hd + lg * 8;

    f32x4 acc0 = {}, acc1 = {}, acc2 = {}, acc3 = {};

    auto ldA = [&](int mtt, int ks) {
        return *(const bf16x8*)(pa + mtt * 16 * Hd + ks * 32);
    };
    auto ldW = [&](int ks) -> bf16x8 {
        if constexpr (WF32) {
            const float* p = (const float*)Wp + wrow + ks * 32;
            float4 x = *(const float4*)p;
            float4 y = *(const float4*)(p + 4);
            bf16x8 r;
            r[0]=f2bf(x.x); r[1]=f2bf(x.y); r[2]=f2bf(x.z); r[3]=f2bf(x.w);
            r[4]=f2bf(y.x); r[5]=f2bf(y.y); r[6]=f2bf(y.z); r[7]=f2bf(y.w);
            return r;
        } else {
            return *(const bf16x8*)((const short*)Wp + wrow + ks * 32);
        }
    };

    bf16x8 a00=ldA(0,0), a01=ldA(1,0), a02=ldA(2,0), a03=ldA(3,0), w0=ldW(0);
    bf16x8 a10=ldA(0,1), a11=ldA(1,1), a12=ldA(2,1), a13=ldA(3,1), w1=ldW(1);

    #pragma unroll
    for (int ks = 0; ks < 32; ks += 2) {
        const int k2 = (ks + 2) & 31;
        const int k3 = (ks + 3) & 31;
        acc0 = MFMA(a00, w0, acc0);
        acc1 = MFMA(a01, w0, acc1);
        acc2 = MFMA(a02, w0, acc2);
        acc3 = MFMA(a03, w0, acc3);
        a00=ldA(0,k2); a01=ldA(1,k2); a02=ldA(2,k2); a03=ldA(3,k2); w0=ldW(k2);
        acc0 = MFMA(a10, w1, acc0);
        acc1 = MFMA(a11, w1, acc1);
        acc2 = MFMA(a12, w1, acc2);
        acc3 = MFMA(a13, w1, acc3);
        a10=ldA(0,k3); a11=ldA(1,k3); a12=ldA(2,k3); a13=ldA(3,k3); w1=ldW(k3);
    }

    const float bn = bias[n0 + lr];
    #pragma unroll
    for (int v = 0; v < 4; ++v) {
        C[(size_t)( 0 + lg * 4 + v) * N + n0 + lr] = acc0[v] + bn;
        C[(size_t)(16 + lg * 4 + v) * N + n0 + lr] = acc1[v] + bn;
        C[(size_t)(32 + lg * 4 + v) * N + n0 + lr] = acc2[v] + bn;
        C[(size_t)(48 + lg * 4 + v) * N + n0 + lr] = acc3[v] + bn;
    }
}

// ---------------------------------------------------------------------------
// Row log-softmax over V=20000, out[b][step][v].
// ---------------------------------------------------------------------------
__global__ __launch_bounds__(256)
void log_softmax_k(const float* __restrict__ logits, float* __restrict__ out, int step)
{
    __shared__ float red[4];
    const int b   = blockIdx.x;
    const int tid = threadIdx.x;
    const float* row = logits + (size_t)b * Vv;

    float m = -1e30f;
    for (int v = tid; v < Vv; v += 256) m = fmaxf(m, row[v]);
    #pragma unroll
    for (int off = 32; off > 0; off >>= 1) m = fmaxf(m, __shfl_down(m, off, 64));
    if ((tid & 63) == 0) red[tid >> 6] = m;
    __syncthreads();
    m = fmaxf(fmaxf(red[0], red[1]), fmaxf(red[2], red[3]));
    __syncthreads();

    float s = 0.f;
    for (int v = tid; v < Vv; v += 256) s += expf(row[v] - m);
    #pragma unroll
    for (int off = 32; off > 0; off >>= 1) s += __shfl_down(s, off, 64);
    if ((tid & 63) == 0) red[tid >> 6] = s;
    __syncthreads();
    s = red[0] + red[1] + red[2] + red[3];
    const float lse = m + logf(s);

    float* orow = out + ((size_t)b * ML + step) * Vv;
    for (int v = tid; v < Vv; v += 256) orow[v] = row[v] - lse;
}

// ---------------------------------------------------------------------------
extern "C" void kernel_launch(void* const* d_in, const int* in_sizes, int n_in,
                              void* d_out, int out_size, void* d_ws, size_t ws_size,
                              hipStream_t stream)
{
    (void)in_sizes; (void)n_in; (void)out_size; (void)ws_size;
    const float* vid   = (const float*)d_in[0];
    const float* W_ih1 = (const float*)d_in[1];
    const float* W_hh1 = (const float*)d_in[2];
    const float* b_ih1 = (const float*)d_in[3];
    const float* b_hh1 = (const float*)d_in[4];
    const float* W_ih2 = (const float*)d_in[5];   // (3072,1536); cols 0..1023 used
    const float* W_hh2 = (const float*)d_in[6];
    const float* b_ih2 = (const float*)d_in[7];
    const float* b_hh2 = (const float*)d_in[8];
    const float* W_obj = (const float*)d_in[9];
    const float* b_obj = (const float*)d_in[10];
    const float* W_rel = (const float*)d_in[11];
    const float* b_rel = (const float*)d_in[12];
    float* out = (float*)d_out;

    // workspace carve-up
    char* p = (char*)d_ws;
    short* vid_bf   = (short*)p; p += (size_t)2048 * Dv * 2;        // 8.0 MB
    short* Wih1_bf  = (short*)p; p += (size_t)G3 * Dv * 2;          // 12.6 MB
    short* Whh1_bf  = (short*)p; p += (size_t)G3 * Hd * 2;          // 6.3 MB
    short* Wih2c_bf = (short*)p; p += (size_t)G3 * Hd * 2;          // 6.3 MB
    short* Whh2_bf  = (short*)p; p += (size_t)G3 * Hd * 2;          // 6.3 MB
    short* out1_bf  = (short*)p; p += (size_t)2048 * Hd * 2;        // 4.2 MB
    short* h1a      = (short*)p; p += (size_t)64 * Hd * 2;
    short* h1b      = (short*)p; p += (size_t)64 * Hd * 2;
    short* h2a      = (short*)p; p += (size_t)64 * Hd * 2;
    short* h2b      = (short*)p; p += (size_t)64 * Hd * 2;
    float* xp1      = (float*)p; p += (size_t)2048 * G3 * 4;        // 25.2 MB (also xp2)
    float* xp2t     = (float*)p; p += (size_t)64 * G3 * 4;
    float* logits   = (float*)p; p += (size_t)64 * Vv * 4;

    hipMemsetAsync(h1a, 0, (size_t)64 * Hd * 2, stream);
    hipMemsetAsync(h2a, 0, (size_t)64 * Hd * 2, stream);

    // conversions to bf16
    {
        long t8;
        t8 = (long)2048 * Dv / 8;
        cvt_f32_bf16<<<(t8 + 255) / 256, 256, 0, stream>>>(vid, vid_bf, t8, t8, 0, 0);
        t8 = (long)G3 * Dv / 8;
        cvt_f32_bf16<<<(t8 + 255) / 256, 256, 0, stream>>>(W_ih1, Wih1_bf, t8, t8, 0, 0);
        t8 = (long)G3 * Hd / 8;
        cvt_f32_bf16<<<(t8 + 255) / 256, 256, 0, stream>>>(W_hh1, Whh1_bf, t8, t8, 0, 0);
        cvt_f32_bf16<<<(t8 + 255) / 256, 256, 0, stream>>>(W_hh2, Whh2_bf, t8, t8, 0, 0);
        // W_ih2: slice first 1024 of 1536 cols, 3072 rows
        cvt_f32_bf16<<<(t8 + 255) / 256, 256, 0, stream>>>(W_ih2, Wih2c_bf, t8, Hd / 8,
                                                           Hd + 512, Hd);
    }

    // Phase 1: xp1 = vid @ W_ih1^T + b_ih1   (M=2048, N=3072, K=2048)
    gemm_mfma_128<<<dim3(G3 / 128, 2048 / 128), 256, 0, stream>>>(
        vid_bf, Dv, Wih1_bf, Dv, b_ih1, xp1, G3, Dv);

    // Phase 2: layer-1 scan; xp row = b*32 + t
    short* h = h1a; short* hn = h1b;
    for (int t = 0; t < Tt; ++t) {
        gru_step_mfma<<<64, 256, 0, stream>>>(xp1, Tt, t, h, Whh1_bf, b_hh1, hn,
                                              out1_bf, t);
        short* tmp = h; h = hn; hn = tmp;
    }

    // Phase 3: xp2 = out1 @ W_ih2[:, :H]^T + b_ih2  (M=2048, N=3072, K=1024)
    float* xp2 = xp1;
    gemm_mfma_128<<<dim3(G3 / 128, 2048 / 128), 256, 0, stream>>>(
        out1_bf, Hd, Wih2c_bf, Hd, b_ih2, xp2, G3, Hd);

    // Phase 4: layer-2 scan; xp row = t*64 + b
    short* g = h2a; short* gn = h2b;
    for (int t = 0; t < Tt; ++t) {
        gru_step_mfma<<<64, 256, 0, stream>>>(xp2, 1, t * 64, g, Whh2_bf, b_hh2, gn,
                                              nullptr, 0);
        short* tmp = g; g = gn; gn = tmp;
    }

    // Phase 5: decode
    for (int i = 0; i < ML; ++i) {
        gru_step_mfma<<<64, 256, 0, stream>>>(b_ih1, 0, 0, h, Whh1_bf, b_hh1, hn,
                                              nullptr, 0);
        { short* tmp = h; h = hn; hn = tmp; }
        skinny_mfma<false><<<G3 / 16, 64, 0, stream>>>(h, (const void*)Wih2c_bf,
                                                       b_ih2, xp2t, G3);
        gru_step_mfma<<<64, 256, 0, stream>>>(xp2t, 1, 0, g, Whh2_bf, b_hh2, gn,
                                              nullptr, 0);
        { short* tmp = g; g = gn; gn = tmp; }
        const float* Wo = (i == 1) ? W_rel : W_obj;
        const float* bo = (i == 1) ? b_rel : b_obj;
        skinny_mfma<true><<<Vv / 16, 64, 0, stream>>>(g, (const void*)Wo, bo,
                                                      logits, Vv);
        log_softmax_k<<<64, 256, 0, stream>>>(logits, out, i);
    }
}

// Round 3
// 1133.242 us; speedup vs baseline: 2.6558x; 1.4276x over previous
//
#include <hip/hip_runtime.h>
#include <math.h>

#define Bsz 64
#define Tt  32
#define Dv  2048
#define Hd  1024
#define G3  3072
#define Vv  20000
#define ML  3

typedef __attribute__((ext_vector_type(8))) short bf16x8;
typedef __attribute__((ext_vector_type(4))) float f32x4;
#define MFMA(a,b,c) __builtin_amdgcn_mfma_f32_16x16x32_bf16(a,b,c,0,0,0)

__device__ __forceinline__ short f2bf(float f) {
    union { float f; unsigned u; } v; v.f = f;
    unsigned r = v.u + 0x7fffu + ((v.u >> 16) & 1u);
    return (short)(r >> 16);
}
__device__ __forceinline__ float bf2f(short s) {
    union { unsigned u; float f; } v; v.u = ((unsigned)(unsigned short)s) << 16;
    return v.f;
}

// ---------------------------------------------------------------------------
// fp32 -> bf16 conversion, 8 elems/thread, optional row slicing (for W_ih2).
// ---------------------------------------------------------------------------
__global__ __launch_bounds__(256)
void cvt_f32_bf16(const float* __restrict__ src, short* __restrict__ dst,
                  long total8, long cols8, int src_ld, int dst_ld)
{
    long i = (long)blockIdx.x * 256 + threadIdx.x;
    if (i >= total8) return;
    long r = i / cols8; long c = i - r * cols8;
    const float* s = src + r * (long)src_ld + c * 8;
    float4 x = *(const float4*)s;
    float4 y = *(const float4*)(s + 4);
    bf16x8 o;
    o[0]=f2bf(x.x); o[1]=f2bf(x.y); o[2]=f2bf(x.z); o[3]=f2bf(x.w);
    o[4]=f2bf(y.x); o[5]=f2bf(y.y); o[6]=f2bf(y.z); o[7]=f2bf(y.w);
    *(bf16x8*)(dst + r * (long)dst_ld + c * 8) = o;
}

// ---------------------------------------------------------------------------
// Big MFMA GEMM (unchanged from round 2): C[M,N] = A*W^T + bias, 128x128 tile.
// ---------------------------------------------------------------------------
__global__ __launch_bounds__(256)
void gemm_mfma_128(const short* __restrict__ A, int lda,
                   const short* __restrict__ W, int ldw,
                   const float* __restrict__ bias,
                   float* __restrict__ C, int ldc, int K)
{
    __shared__ __align__(16) short As[128 * 40];
    __shared__ __align__(16) short Bs[128 * 40];
    const int tid = threadIdx.x;
    const int w = tid >> 6, l = tid & 63;
    const int wm = w >> 1, wn = w & 1;
    const int lr = l & 15, lg = l >> 4;
    const int m0 = blockIdx.y * 128, n0 = blockIdx.x * 128;
    const int sm = tid >> 2;
    const int skg = tid & 3;

    f32x4 acc[4][4] = {};

    for (int k0 = 0; k0 < K; k0 += 32) {
        #pragma unroll
        for (int i = 0; i < 2; ++i) {
            const int m = i * 64 + sm;
            bf16x8 av = *(const bf16x8*)(A + (size_t)(m0 + m) * lda + k0 + skg * 8);
            bf16x8 wv = *(const bf16x8*)(W + (size_t)(n0 + m) * ldw + k0 + skg * 8);
            *(bf16x8*)(As + m * 40 + skg * 8) = av;
            *(bf16x8*)(Bs + m * 40 + skg * 8) = wv;
        }
        __syncthreads();
        bf16x8 af[4], bfr[4];
        #pragma unroll
        for (int mt = 0; mt < 4; ++mt) {
            const int m = wm * 64 + mt * 16 + lr;
            const int n = wn * 64 + mt * 16 + lr;
            af[mt]  = *(const bf16x8*)(As + m * 40 + lg * 8);
            bfr[mt] = *(const bf16x8*)(Bs + n * 40 + lg * 8);
        }
        #pragma unroll
        for (int mt = 0; mt < 4; ++mt)
            #pragma unroll
            for (int nt = 0; nt < 4; ++nt)
                acc[mt][nt] = MFMA(af[mt], bfr[nt], acc[mt][nt]);
        __syncthreads();
    }

    #pragma unroll
    for (int mt = 0; mt < 4; ++mt)
        #pragma unroll
        for (int nt = 0; nt < 4; ++nt)
            #pragma unroll
            for (int v = 0; v < 4; ++v) {
                const int m = m0 + wm * 64 + mt * 16 + lg * 4 + v;
                const int n = n0 + wn * 64 + nt * 16 + lr;
                C[(size_t)m * ldc + n] = acc[mt][nt][v] + bias[n];
            }
}

// ---------------------------------------------------------------------------
// Persistent GRU scan: T steps in ONE launch. 64 blocks x 256 thr (4 waves).
// Block bj owns 16 gate-columns j0=bj*16 for all 3 gates; its W slice
// (48 rows x 1024 bf16 = 96 KB) is staged into LDS ONCE (XOR-swizzled rows:
// byte ^= (row&7)<<4 -> conflict-free ds_read_b128). h lives in global bf16
// double buffers [64][1024]; steps are separated by a hand-rolled grid
// barrier (release-add / acquire-spin, agent scope -> cross-XCD wbl2/inv).
// All 64 blocks are co-resident (64 << 256 CUs), so the barrier cannot hang.
// xp row for (batch b, step s) = b*xp_rs + s*xp_ts (both 0 -> broadcast bias).
// ---------------------------------------------------------------------------
__global__ __launch_bounds__(256)
void gru_scan(const float* __restrict__ xp, int xp_rs, int xp_ts,
              const short* __restrict__ Whh,   // bf16 [3072][1024]
              const float* __restrict__ b_hh,
              short* __restrict__ hb0, short* __restrict__ hb1, int p0,
              short* __restrict__ out_seq,     // bf16 (T*64,1024) or null
              int T, unsigned int* __restrict__ ctr)
{
    __shared__ __align__(16) short Wl[48 * 1024];   // 98304 B
    const int tid = threadIdx.x;
    const int mt = tid >> 6;
    const int l  = tid & 63;
    const int lr = l & 15, lg = l >> 4;
    const int j0 = blockIdx.x * 16;
    const int j  = j0 + lr;

    // ---- stage W slice into LDS (once per launch), swizzled ----
    #pragma unroll
    for (int i = 0; i < 24; ++i) {
        const int q   = tid + i * 256;        // 16B-chunk id, 0..6143
        const int row = q >> 7;               // 0..47 (gate*16 + rr)
        const int c16 = q & 127;
        const int grow = ((row >> 4) << 10) + j0 + (row & 15);
        bf16x8 v = *(const bf16x8*)(Whh + (size_t)grow * Hd + c16 * 8);
        const int byte = row * 2048 + ((c16 << 4) ^ ((row & 7) << 4));
        *(bf16x8*)((char*)Wl + byte) = v;
    }
    __syncthreads();

    // per-lane constants
    const int lrb   = lr * 2048;
    const int sw    = (lr & 7) << 4;
    const int lgoff = lg << 4;
    const float bh0 = b_hh[j], bh1 = b_hh[Hd + j], bh2 = b_hh[2 * Hd + j];

    for (int s = 0; s < T; ++s) {
        const short* hin  = ((p0 + s) & 1) ? hb1 : hb0;
        short*       hout = ((p0 + s) & 1) ? hb0 : hb1;
        const short* pa = hin + (size_t)(mt * 16 + lr) * Hd + lg * 8;

        f32x4 ar = {}, az = {}, an = {};
        bf16x8 a[4];
        #pragma unroll
        for (int i = 0; i < 4; ++i) a[i] = *(const bf16x8*)(pa + i * 32);

        #pragma unroll
        for (int kb = 0; kb < 32; kb += 4) {
            bf16x8 nx[4];
            #pragma unroll
            for (int i = 0; i < 4; ++i)
                nx[i] = *(const bf16x8*)(pa + ((kb + 4 + i) & 31) * 32);
            #pragma unroll
            for (int u = 0; u < 4; ++u) {
                const int k = kb + u;
                const int off = ((k << 6) + lgoff) ^ sw;
                bf16x8 b0 = *(const bf16x8*)((const char*)Wl + 0     + lrb + off);
                bf16x8 b1 = *(const bf16x8*)((const char*)Wl + 32768 + lrb + off);
                bf16x8 b2 = *(const bf16x8*)((const char*)Wl + 65536 + lrb + off);
                ar = MFMA(a[u], b0, ar);
                az = MFMA(a[u], b1, az);
                an = MFMA(a[u], b2, an);
            }
            #pragma unroll
            for (int i = 0; i < 4; ++i) a[i] = nx[i];
        }

        // epilogue: gates + h update
        #pragma unroll
        for (int v = 0; v < 4; ++v) {
            const int b = mt * 16 + lg * 4 + v;
            const float* xrow = xp + (size_t)(b * xp_rs + s * xp_ts) * G3;
            const float xr = xrow[j];
            const float xz = xrow[Hd + j];
            const float xn = xrow[2 * Hd + j];
            const float rg = 1.f / (1.f + __expf(-(xr + ar[v] + bh0)));
            const float zg = 1.f / (1.f + __expf(-(xz + az[v] + bh1)));
            const float ng = tanhf(xn + rg * (an[v] + bh2));
            const float hp = bf2f(hin[(size_t)b * Hd + j]);
            const float hv = (1.f - zg) * ng + zg * hp;
            const short hb = f2bf(hv);
            hout[(size_t)b * Hd + j] = hb;
            if (out_seq) out_seq[((size_t)s * 64 + b) * Hd + j] = hb;
        }

        // grid barrier (skip after last step)
        if (s != T - 1) {
            __syncthreads();              // all block stores drained to L2
            if (tid == 0) {
                __hip_atomic_fetch_add(ctr, 1u, __ATOMIC_RELEASE,
                                       __HIP_MEMORY_SCOPE_AGENT);   // wbl2 + add
                const unsigned tgt = (unsigned)(s + 1) * gridDim.x;
                while (__hip_atomic_load(ctr, __ATOMIC_ACQUIRE,
                                         __HIP_MEMORY_SCOPE_AGENT) < tgt) {}
            }
            __syncthreads();              // whole block sees fresh h
        }
    }
}

// ---------------------------------------------------------------------------
// Skinny MFMA GEMM (unchanged): C[64,N]f32 = A[64,1024]bf16 * W[N,1024]^T + b.
// ---------------------------------------------------------------------------
template<bool WF32>
__global__ __launch_bounds__(64)
void skinny_mfma(const short* __restrict__ A,
                 const void* __restrict__ Wp,
                 const float* __restrict__ bias,
                 float* __restrict__ C, int N)
{
    const int l = threadIdx.x;
    const int lr = l & 15, lg = l >> 4;
    const int n0 = blockIdx.x * 16;
    const size_t wrow = (size_t)(n0 + lr) * Hd + lg * 8;
    const short* pa = A + (size_t)lr * Hd + lg * 8;

    f32x4 acc0 = {}, acc1 = {}, acc2 = {}, acc3 = {};

    auto ldA = [&](int mtt, int ks) {
        return *(const bf16x8*)(pa + mtt * 16 * Hd + ks * 32);
    };
    auto ldW = [&](int ks) -> bf16x8 {
        if constexpr (WF32) {
            const float* p = (const float*)Wp + wrow + ks * 32;
            float4 x = *(const float4*)p;
            float4 y = *(const float4*)(p + 4);
            bf16x8 r;
            r[0]=f2bf(x.x); r[1]=f2bf(x.y); r[2]=f2bf(x.z); r[3]=f2bf(x.w);
            r[4]=f2bf(y.x); r[5]=f2bf(y.y); r[6]=f2bf(y.z); r[7]=f2bf(y.w);
            return r;
        } else {
            return *(const bf16x8*)((const short*)Wp + wrow + ks * 32);
        }
    };

    bf16x8 a00=ldA(0,0), a01=ldA(1,0), a02=ldA(2,0), a03=ldA(3,0), w0=ldW(0);
    bf16x8 a10=ldA(0,1), a11=ldA(1,1), a12=ldA(2,1), a13=ldA(3,1), w1=ldW(1);

    #pragma unroll
    for (int ks = 0; ks < 32; ks += 2) {
        const int k2 = (ks + 2) & 31;
        const int k3 = (ks + 3) & 31;
        acc0 = MFMA(a00, w0, acc0);
        acc1 = MFMA(a01, w0, acc1);
        acc2 = MFMA(a02, w0, acc2);
        acc3 = MFMA(a03, w0, acc3);
        a00=ldA(0,k2); a01=ldA(1,k2); a02=ldA(2,k2); a03=ldA(3,k2); w0=ldW(k2);
        acc0 = MFMA(a10, w1, acc0);
        acc1 = MFMA(a11, w1, acc1);
        acc2 = MFMA(a12, w1, acc2);
        acc3 = MFMA(a13, w1, acc3);
        a10=ldA(0,k3); a11=ldA(1,k3); a12=ldA(2,k3); a13=ldA(3,k3); w1=ldW(k3);
    }

    const float bn = bias[n0 + lr];
    #pragma unroll
    for (int v = 0; v < 4; ++v) {
        C[(size_t)( 0 + lg * 4 + v) * N + n0 + lr] = acc0[v] + bn;
        C[(size_t)(16 + lg * 4 + v) * N + n0 + lr] = acc1[v] + bn;
        C[(size_t)(32 + lg * 4 + v) * N + n0 + lr] = acc2[v] + bn;
        C[(size_t)(48 + lg * 4 + v) * N + n0 + lr] = acc3[v] + bn;
    }
}

// ---------------------------------------------------------------------------
// Row log-softmax over V=20000, out[b][step][v].
// ---------------------------------------------------------------------------
__global__ __launch_bounds__(256)
void log_softmax_k(const float* __restrict__ logits, float* __restrict__ out, int step)
{
    __shared__ float red[4];
    const int b   = blockIdx.x;
    const int tid = threadIdx.x;
    const float* row = logits + (size_t)b * Vv;

    float m = -1e30f;
    for (int v = tid; v < Vv; v += 256) m = fmaxf(m, row[v]);
    #pragma unroll
    for (int off = 32; off > 0; off >>= 1) m = fmaxf(m, __shfl_down(m, off, 64));
    if ((tid & 63) == 0) red[tid >> 6] = m;
    __syncthreads();
    m = fmaxf(fmaxf(red[0], red[1]), fmaxf(red[2], red[3]));
    __syncthreads();

    float s = 0.f;
    for (int v = tid; v < Vv; v += 256) s += expf(row[v] - m);
    #pragma unroll
    for (int off = 32; off > 0; off >>= 1) s += __shfl_down(s, off, 64);
    if ((tid & 63) == 0) red[tid >> 6] = s;
    __syncthreads();
    s = red[0] + red[1] + red[2] + red[3];
    const float lse = m + logf(s);

    float* orow = out + ((size_t)b * ML + step) * Vv;
    for (int v = tid; v < Vv; v += 256) orow[v] = row[v] - lse;
}

// ---------------------------------------------------------------------------
extern "C" void kernel_launch(void* const* d_in, const int* in_sizes, int n_in,
                              void* d_out, int out_size, void* d_ws, size_t ws_size,
                              hipStream_t stream)
{
    (void)in_sizes; (void)n_in; (void)out_size; (void)ws_size;
    const float* vid   = (const float*)d_in[0];
    const float* W_ih1 = (const float*)d_in[1];
    const float* W_hh1 = (const float*)d_in[2];
    const float* b_ih1 = (const float*)d_in[3];
    const float* b_hh1 = (const float*)d_in[4];
    const float* W_ih2 = (const float*)d_in[5];   // (3072,1536); cols 0..1023 used
    const float* W_hh2 = (const float*)d_in[6];
    const float* b_ih2 = (const float*)d_in[7];
    const float* b_hh2 = (const float*)d_in[8];
    const float* W_obj = (const float*)d_in[9];
    const float* b_obj = (const float*)d_in[10];
    const float* W_rel = (const float*)d_in[11];
    const float* b_rel = (const float*)d_in[12];
    float* out = (float*)d_out;

    // workspace carve-up
    char* p = (char*)d_ws;
    short* vid_bf   = (short*)p; p += (size_t)2048 * Dv * 2;        // 8.0 MB
    short* Wih1_bf  = (short*)p; p += (size_t)G3 * Dv * 2;          // 12.6 MB
    short* Whh1_bf  = (short*)p; p += (size_t)G3 * Hd * 2;          // 6.3 MB
    short* Wih2c_bf = (short*)p; p += (size_t)G3 * Hd * 2;          // 6.3 MB
    short* Whh2_bf  = (short*)p; p += (size_t)G3 * Hd * 2;          // 6.3 MB
    short* out1_bf  = (short*)p; p += (size_t)2048 * Hd * 2;        // 4.2 MB
    // --- zero zone (one memset): h double-buffers + barrier counters ---
    char* zz = p;
    short* h1a = (short*)p; p += (size_t)64 * Hd * 2;
    short* h1b = (short*)p; p += (size_t)64 * Hd * 2;
    short* h2a = (short*)p; p += (size_t)64 * Hd * 2;
    short* h2b = (short*)p; p += (size_t)64 * Hd * 2;
    unsigned int* ctr = (unsigned int*)p; p += 256;                 // ctr[0], ctr[1]
    size_t zz_bytes = (size_t)(p - zz);
    float* xp1    = (float*)p; p += (size_t)2048 * G3 * 4;          // 25.2 MB (also xp2)
    float* xp2t   = (float*)p; p += (size_t)64 * G3 * 4;
    float* logits = (float*)p; p += (size_t)64 * Vv * 4;

    hipMemsetAsync(zz, 0, zz_bytes, stream);

    // conversions to bf16
    {
        long t8;
        t8 = (long)2048 * Dv / 8;
        cvt_f32_bf16<<<(t8 + 255) / 256, 256, 0, stream>>>(vid, vid_bf, t8, t8, 0, 0);
        t8 = (long)G3 * Dv / 8;
        cvt_f32_bf16<<<(t8 + 255) / 256, 256, 0, stream>>>(W_ih1, Wih1_bf, t8, t8, 0, 0);
        t8 = (long)G3 * Hd / 8;
        cvt_f32_bf16<<<(t8 + 255) / 256, 256, 0, stream>>>(W_hh1, Whh1_bf, t8, t8, 0, 0);
        cvt_f32_bf16<<<(t8 + 255) / 256, 256, 0, stream>>>(W_hh2, Whh2_bf, t8, t8, 0, 0);
        cvt_f32_bf16<<<(t8 + 255) / 256, 256, 0, stream>>>(W_ih2, Wih2c_bf, t8, Hd / 8,
                                                           Hd + 512, Hd);
    }

    // Phase 1: xp1 = vid @ W_ih1^T + b_ih1   (M=2048, N=3072, K=2048)
    gemm_mfma_128<<<dim3(G3 / 128, 2048 / 128), 256, 0, stream>>>(
        vid_bf, Dv, Wih1_bf, Dv, b_ih1, xp1, G3, Dv);

    // Phase 2: layer-1 scan, ONE launch (xp row = b*32 + s), writes out1
    gru_scan<<<64, 256, 0, stream>>>(xp1, Tt, 1, Whh1_bf, b_hh1,
                                     h1a, h1b, 0, out1_bf, Tt, ctr + 0);
    int p1 = 0;  // (0 + 32) & 1 == 0 -> final h1 in h1a

    // Phase 3: xp2 = out1 @ W_ih2[:, :H]^T + b_ih2  (M=2048, N=3072, K=1024)
    float* xp2 = xp1;
    gemm_mfma_128<<<dim3(G3 / 128, 2048 / 128), 256, 0, stream>>>(
        out1_bf, Hd, Wih2c_bf, Hd, b_ih2, xp2, G3, Hd);

    // Phase 4: layer-2 scan, ONE launch (xp row = s*64 + b)
    gru_scan<<<64, 256, 0, stream>>>(xp2, 1, 64, Whh2_bf, b_hh2,
                                     h2a, h2b, 0, nullptr, Tt, ctr + 1);
    int p2 = 0;

    // Phase 5: decode (gru_scan with T=1; barrier not executed)
    for (int i = 0; i < ML; ++i) {
        gru_scan<<<64, 256, 0, stream>>>(b_ih1, 0, 0, Whh1_bf, b_hh1,
                                         h1a, h1b, p1, nullptr, 1, ctr);
        p1 ^= 1;
        short* h1cur = p1 ? h1b : h1a;
        skinny_mfma<false><<<G3 / 16, 64, 0, stream>>>(h1cur, (const void*)Wih2c_bf,
                                                       b_ih2, xp2t, G3);
        gru_scan<<<64, 256, 0, stream>>>(xp2t, 1, 0, Whh2_bf, b_hh2,
                                         h2a, h2b, p2, nullptr, 1, ctr);
        p2 ^= 1;
        short* h2cur = p2 ? h2b : h2a;
        const float* Wo = (i == 1) ? W_rel : W_obj;
        const float* bo = (i == 1) ? b_rel : b_obj;
        skinny_mfma<true><<<Vv / 16, 64, 0, stream>>>(h2cur, (const void*)Wo, bo,
                                                      logits, Vv);
        log_softmax_k<<<64, 256, 0, stream>>>(logits, out, i);
    }
}